// Round 15
// baseline (393.169 us; speedup 1.0000x reference)
//
#include <hip/hip_runtime.h>
#include <stdint.h>

typedef unsigned short u16;

#define E_    8
#define DIM_  1024
#define HID_  2048
#define H2_   4096     // 2*HID
#define NTOK  8192     // B*T
#define SLAB  ((size_t)NTOK * 2 * DIM_)   // u16 elems per ybuf slab

typedef __attribute__((ext_vector_type(8))) short bf16x8;
typedef __attribute__((ext_vector_type(4))) float f32x4;

__device__ __forceinline__ u16 f2bf(float f) {
  uint32_t u = __builtin_bit_cast(uint32_t, f);
  uint32_t r = (u + 0x7FFFu + ((u >> 16) & 1u)) >> 16;
  return (u16)r;
}
__device__ __forceinline__ float bf2f(u16 u) {
  return __builtin_bit_cast(float, (uint32_t)u << 16);
}

__device__ __forceinline__ void gload16(const void* g, void* l) {
  __builtin_amdgcn_global_load_lds(
      (const __attribute__((address_space(1))) void*)g,
      (__attribute__((address_space(3))) void*)l, 16, 0, 0);
}

// ---------------- prep: fused weight transpose + router pass A ----------------

__global__ void prep(const float* __restrict__ W1, u16* __restrict__ w1t,
                     const float* __restrict__ W2, u16* __restrict__ w2t,
                     const float* __restrict__ x, const float* __restrict__ rw,
                     const float* __restrict__ rb, u16* __restrict__ xb,
                     int* __restrict__ gcnt, int2* __restrict__ te_l,
                     float2* __restrict__ tw) {
  __shared__ float smem[E_ * DIM_ + 16];
  int b = blockIdx.x;
  int tid = threadIdx.x;

  if (b < 12288) {
    float (*t)[65] = (float(*)[65])smem;
    const float* src; u16* dst; int R, C, e, bx, by;
    if (b < 8192) {
      e = b >> 10; int rem = b & 1023;
      bx = rem & 63; by = rem >> 6;
      src = W1; dst = w1t; R = DIM_; C = H2_;
    } else {
      int b2 = b - 8192;
      e = b2 >> 9; int rem = b2 & 511;
      bx = rem & 15; by = rem >> 4;
      src = W2; dst = w2t; R = HID_; C = DIM_;
    }
    int r0 = by * 64, c0 = bx * 64;
    const float* s = src + (size_t)e * R * C;
    u16* d = dst + (size_t)e * R * C;
    int rr = tid >> 4, cc = (tid & 15) * 4;
#pragma unroll
    for (int p = 0; p < 4; ++p) {
      float4 v = *(const float4*)(s + (size_t)(r0 + p * 16 + rr) * C + c0 + cc);
      t[p * 16 + rr][cc + 0] = v.x; t[p * 16 + rr][cc + 1] = v.y;
      t[p * 16 + rr][cc + 2] = v.z; t[p * 16 + rr][cc + 3] = v.w;
    }
    __syncthreads();
    int cr = tid >> 3, rc = (tid & 7) * 8;
#pragma unroll
    for (int p = 0; p < 2; ++p) {
      union { u16 u[8]; uint4 v; } w;
#pragma unroll
      for (int j = 0; j < 8; ++j) w.u[j] = f2bf(t[rc + j][p * 32 + cr]);
      *(uint4*)(d + (size_t)(c0 + p * 32 + cr) * R + r0 + rc) = w.v;
    }
  } else {
    int rblk = b - 12288;
    float* srw = smem;
    float* sb  = smem + E_ * DIM_;
    int*   hcnt = (int*)(smem + E_ * DIM_ + 8);

    for (int i = tid; i < E_ * DIM_ / 4; i += 256)
      ((float4*)srw)[i] = ((const float4*)rw)[i];
    if (tid < E_) { sb[tid] = rb[tid]; hcnt[tid] = 0; }
    __syncthreads();

    int wid = tid >> 6, lane = tid & 63;
#pragma unroll
    for (int s = 0; s < 2; ++s) {
      int t = rblk * 8 + wid * 2 + s;
      const float* xt = x + (size_t)t * DIM_;
      float acc[8] = {0.f, 0.f, 0.f, 0.f, 0.f, 0.f, 0.f, 0.f};
#pragma unroll
      for (int it = 0; it < 4; ++it) {
        int d = it * 256 + lane * 4;
        float4 xv = *(const float4*)(xt + d);
        ushort4 xo;
        xo.x = f2bf(xv.x); xo.y = f2bf(xv.y); xo.z = f2bf(xv.z); xo.w = f2bf(xv.w);
        *(ushort4*)(xb + (size_t)t * DIM_ + d) = xo;
#pragma unroll
        for (int e = 0; e < 8; ++e) {
          float4 rv = *(const float4*)(&srw[e * DIM_ + d]);
          acc[e] += xv.x * rv.x + xv.y * rv.y + xv.z * rv.z + xv.w * rv.w;
        }
      }
#pragma unroll
      for (int e = 0; e < 8; ++e)
#pragma unroll
        for (int off = 32; off; off >>= 1)
          acc[e] += __shfl_xor(acc[e], off, 64);
      if (lane == 0) {
        float v[8];
#pragma unroll
        for (int e = 0; e < 8; ++e) v[e] = acc[e] + sb[e];
        int i0 = 0;
#pragma unroll
        for (int e = 1; e < 8; ++e) if (v[e] > v[i0]) i0 = e;
        int i1 = (i0 == 0) ? 1 : 0;
#pragma unroll
        for (int e = 0; e < 8; ++e) if (e != i0 && v[e] > v[i1]) i1 = e;
        float w0 = 1.f / (1.f + expf(v[i1] - v[i0]));
        int l0 = atomicAdd(&hcnt[i0], 1);
        int l1 = atomicAdd(&hcnt[i1], 1);
        te_l[t] = make_int2((i0 << 8) | l0, (i1 << 8) | l1);
        tw[t] = make_float2(w0, 1.f - w0);
      }
    }
    __syncthreads();
    if (tid < E_) gcnt[tid * 1024 + rblk] = hcnt[tid];
  }
}

// ---------------- routerBC: redundant 8-expert batched scan + scatter ----------------

__global__ void routerBC(const int* __restrict__ gcnt, int* __restrict__ counts,
                         const int2* __restrict__ te_l, const float2* __restrict__ tw,
                         int* __restrict__ btok, float* __restrict__ bw,
                         int* __restrict__ tokrec) {
  __shared__ int part[8][256];
  __shared__ int sbb[8][32];
  int tid = threadIdx.x, b = blockIdx.x;

  int4 v[8]; int s[8];
#pragma unroll
  for (int e = 0; e < 8; ++e) {
    v[e] = *(const int4*)(gcnt + e * 1024 + tid * 4);
    s[e] = v[e].x + v[e].y + v[e].z + v[e].w;
    part[e][tid] = s[e];
  }
  __syncthreads();
  for (int off = 1; off < 256; off <<= 1) {
    int o[8];
#pragma unroll
    for (int e = 0; e < 8; ++e) o[e] = (tid >= off) ? part[e][tid - off] : 0;
    __syncthreads();
#pragma unroll
    for (int e = 0; e < 8; ++e) part[e][tid] += o[e];
    __syncthreads();
  }
  if ((tid >> 3) == b) {
    int lc = (tid & 7) * 4;
#pragma unroll
    for (int e = 0; e < 8; ++e) {
      int ex = part[e][tid] - s[e];
      sbb[e][lc + 0] = ex;
      sbb[e][lc + 1] = ex + v[e].x;
      sbb[e][lc + 2] = ex + v[e].x + v[e].y;
      sbb[e][lc + 3] = ex + v[e].x + v[e].y + v[e].z;
    }
  }
  if (b == 0 && tid < 8) counts[tid] = part[tid][255];
  __syncthreads();

  int t = b * 256 + tid;
  int2 r = te_l[t];
  float2 w = tw[t];
  int blk_l = tid >> 3;
  int e0 = r.x >> 8, l0 = r.x & 255;
  int e1 = r.y >> 8, l1 = r.y & 255;
  int p0 = sbb[e0][blk_l] + l0;
  int p1 = sbb[e1][blk_l] + l1;
  btok[e0 * NTOK + p0] = t; bw[e0 * NTOK + p0] = w.x; tokrec[t * 2 + 0] = (e0 << 13) | p0;
  btok[e1 * NTOK + p1] = t; bw[e1 * NTOK + p1] = w.y; tokrec[t * 2 + 1] = (e1 << 13) | p1;
}

// ---------------- GEMM1: gathered x @ W1 -> swiglu -> hb ----------------
// 1D grid 16384, XCD-chunked (one expert per XCD), mblk FASTEST within the
// chunk: A (~4 MB/expert) becomes L2-resident, B streamed exactly once.

__launch_bounds__(256, 4)
__global__ void gemm1(const u16* __restrict__ xb, const u16* __restrict__ w1t,
                      const float* __restrict__ b1, const int* __restrict__ counts,
                      const int* __restrict__ btok, u16* __restrict__ hb) {
  int bid = blockIdx.x;
  int swz = (bid & 7) * 2048 + (bid >> 3);
  int e = swz >> 11;
  int rem = swz & 2047;
  int mblk = rem & 63, nblk = rem >> 6;   // mblk fastest

  int cnt = counts[e];
  if (mblk * 128 >= cnt) return;
  int base = 0;
#pragma unroll
  for (int i = 0; i < 8; ++i) base += (i < e) ? counts[i] : 0;

  __shared__ u16 lA[128 * 64];
  __shared__ u16 lB[128 * 64];
  __shared__ int sTok[128];

  int tid = threadIdx.x, wid = tid >> 6, lane = tid & 63;
  if (tid < 128) {
    int gr = mblk * 128 + tid;
    sTok[tid] = (gr < cnt) ? btok[e * NTOK + gr] : btok[e * NTOK];
  }
  __syncthreads();

  f32x4 acc[4][4] = {};
  int wr = wid >> 1, wc = wid & 1;
  int l15 = lane & 15, lhi = lane >> 4;
  const size_t w1e = (size_t)e * H2_ * DIM_;

  int segsw = ((lane & 7) ^ ((lane >> 3) & 7)) * 8;
  const u16* gA[4];
  const u16* gB[4];
#pragma unroll
  for (int i = 0; i < 4; ++i) {
    int r = wid * 32 + i * 8 + (lane >> 3);
    gA[i] = xb + (size_t)sTok[r] * DIM_ + segsw;
    int gcol = nblk * 64 + (r >> 6) * 32 + (r & 31) + ((r >> 5) & 1) * 2048;
    gB[i] = w1t + w1e + (size_t)gcol * DIM_ + segsw;
  }
  int rxor = (l15 & 7) * 8;

  for (int kt = 0; kt < DIM_ / 64; ++kt) {
#pragma unroll
    for (int i = 0; i < 4; ++i)
      gload16(gA[i] + kt * 64, &lA[(wid * 32 + i * 8) * 64]);
#pragma unroll
    for (int i = 0; i < 4; ++i)
      gload16(gB[i] + kt * 64, &lB[(wid * 32 + i * 8) * 64]);
    __syncthreads();
#pragma unroll
    for (int ks = 0; ks < 2; ++ks) {
      int segrd = ((ks * 4 + lhi) * 8) ^ rxor;
      bf16x8 a[4], b[4];
#pragma unroll
      for (int m = 0; m < 4; ++m)
        a[m] = *(const bf16x8*)&lA[(wr * 64 + m * 16 + l15) * 64 + segrd];
#pragma unroll
      for (int n = 0; n < 4; ++n)
        b[n] = *(const bf16x8*)&lB[(wc * 64 + n * 16 + l15) * 64 + segrd];
#pragma unroll
      for (int m = 0; m < 4; ++m)
#pragma unroll
        for (int n = 0; n < 4; ++n)
          acc[m][n] = __builtin_amdgcn_mfma_f32_16x16x32_bf16(a[m], b[n], acc[m][n], 0, 0, 0);
    }
    __syncthreads();
  }

#pragma unroll
  for (int n = 0; n < 2; ++n) {
    int outcol = nblk * 64 + wc * 32 + n * 16 + l15;
    float bb1 = b1[e * H2_ + outcol];
    float bb2 = b1[e * H2_ + outcol + HID_];
#pragma unroll
    for (int m = 0; m < 4; ++m) {
#pragma unroll
      for (int j = 0; j < 4; ++j) {
        int rt = wr * 64 + m * 16 + lhi * 4 + j;
        int gr = mblk * 128 + rt;
        if (gr < cnt) {
          float h1 = acc[m][n][j] + bb1;
          float h2 = acc[m][n + 2][j] + bb2;
          float s = (h1 / (1.f + __expf(-h1))) * h2;
          hb[(size_t)(base + gr) * HID_ + outcol] = f2bf(s);
        }
      }
    }
  }
}

// ---------------- GEMM2 split-K=2, XCD-chunked; khalf outermost in chunk ----------------
// Per half-K sweep: B-half (2 MB) L2-resident, A-half streamed once.

__launch_bounds__(256, 4)
__global__ void gemm2(const u16* __restrict__ hb, const u16* __restrict__ w2t,
                      const float* __restrict__ b2, const int* __restrict__ counts,
                      const float* __restrict__ bw, u16* __restrict__ ybuf) {
  int bid = blockIdx.x;
  int swz = (bid & 7) * 1024 + (bid >> 3);
  int e = swz >> 10;
  int rem = swz & 1023;
  int khalf = rem >> 9;
  int r2 = rem & 511;
  int mblk = r2 >> 3, nblk = r2 & 7;

  int cnt = counts[e];
  if (mblk * 128 >= cnt) return;
  int base = 0;
#pragma unroll
  for (int i = 0; i < 8; ++i) base += (i < e) ? counts[i] : 0;

  __shared__ u16 lA[128 * 64];
  __shared__ u16 lB[128 * 64];
  __shared__ float sW[128];

  int tid = threadIdx.x, wid = tid >> 6, lane = tid & 63;
  if (tid < 128) {
    int gr = mblk * 128 + tid;
    sW[tid] = (gr < cnt) ? bw[e * NTOK + gr] : 0.f;
  }
  __syncthreads();

  f32x4 acc[4][4] = {};
  int wr = wid >> 1, wc = wid & 1;
  int l15 = lane & 15, lhi = lane >> 4;

  int segsw = ((lane & 7) ^ ((lane >> 3) & 7)) * 8;
  int koff = khalf * (HID_ / 2);
  const u16* gA[4];
  const u16* gB[4];
#pragma unroll
  for (int i = 0; i < 4; ++i) {
    int r = wid * 32 + i * 8 + (lane >> 3);
    gA[i] = hb + (size_t)(base + mblk * 128 + r) * HID_ + koff + segsw;
    gB[i] = w2t + (size_t)e * DIM_ * HID_ + (size_t)(nblk * 128 + r) * HID_ + koff + segsw;
  }
  int rxor = (l15 & 7) * 8;

  for (int kt = 0; kt < HID_ / 128; ++kt) {
#pragma unroll
    for (int i = 0; i < 4; ++i) {
      gload16(gA[i] + kt * 64, &lA[(wid * 32 + i * 8) * 64]);
      gload16(gB[i] + kt * 64, &lB[(wid * 32 + i * 8) * 64]);
    }
    __syncthreads();
#pragma unroll
    for (int ks = 0; ks < 2; ++ks) {
      int segrd = ((ks * 4 + lhi) * 8) ^ rxor;
      bf16x8 a[4], b[4];
#pragma unroll
      for (int m = 0; m < 4; ++m)
        a[m] = *(const bf16x8*)&lA[(wr * 64 + m * 16 + l15) * 64 + segrd];
#pragma unroll
      for (int n = 0; n < 4; ++n)
        b[n] = *(const bf16x8*)&lB[(wc * 64 + n * 16 + l15) * 64 + segrd];
#pragma unroll
      for (int m = 0; m < 4; ++m)
#pragma unroll
        for (int n = 0; n < 4; ++n)
          acc[m][n] = __builtin_amdgcn_mfma_f32_16x16x32_bf16(a[m], b[n], acc[m][n], 0, 0, 0);
    }
    __syncthreads();
  }

  u16* yb = ybuf + (size_t)khalf * SLAB;
#pragma unroll
  for (int n = 0; n < 4; ++n) {
    int col = nblk * 128 + wc * 64 + n * 16 + l15;
    float bb = (khalf == 0) ? b2[e * DIM_ + col] : 0.f;
#pragma unroll
    for (int m = 0; m < 4; ++m) {
#pragma unroll
      for (int j = 0; j < 4; ++j) {
        int rt = wr * 64 + m * 16 + lhi * 4 + j;
        int gr = mblk * 128 + rt;
        if (gr < cnt)
          yb[(size_t)(base + gr) * DIM_ + col] = f2bf(sW[rt] * (acc[m][n][j] + bb));
      }
    }
  }
}

// ---------------- combine: out[t] = sum of 4 slices ----------------

__global__ void combine(const u16* __restrict__ ybuf, const int* __restrict__ tokrec,
                        const int* __restrict__ counts, float* __restrict__ out) {
  __shared__ int sbase[8];
  int tid = threadIdx.x;
  if (tid < 8) {
    int b = 0;
#pragma unroll
    for (int e = 0; e < 8; ++e) { if (e == tid) sbase[e] = b; b += counts[e]; }
  }
  __syncthreads();
  int wid = tid >> 6, lane = tid & 63;
  int t = blockIdx.x * 4 + wid;
  int r0 = tokrec[t * 2 + 0], r1 = tokrec[t * 2 + 1];
  size_t s0 = (size_t)(sbase[r0 >> 13] + (r0 & 8191)) * DIM_;
  size_t s1 = (size_t)(sbase[r1 >> 13] + (r1 & 8191)) * DIM_;
#pragma unroll
  for (int p = 0; p < 4; ++p) {
    int c = (lane + p * 64) * 4;
    ushort4 a0 = *(const ushort4*)(ybuf + s0 + c);
    ushort4 a1 = *(const ushort4*)(ybuf + SLAB + s0 + c);
    ushort4 b0 = *(const ushort4*)(ybuf + s1 + c);
    ushort4 b1 = *(const ushort4*)(ybuf + SLAB + s1 + c);
    float4 o;
    o.x = bf2f(a0.x) + bf2f(a1.x) + bf2f(b0.x) + bf2f(b1.x);
    o.y = bf2f(a0.y) + bf2f(a1.y) + bf2f(b0.y) + bf2f(b1.y);
    o.z = bf2f(a0.z) + bf2f(a1.z) + bf2f(b0.z) + bf2f(b1.z);
    o.w = bf2f(a0.w) + bf2f(a1.w) + bf2f(b0.w) + bf2f(b1.w);
    *(float4*)(out + (size_t)t * DIM_ + c) = o;
  }
}

// ---------------- launch ----------------

extern "C" void kernel_launch(void* const* d_in, const int* in_sizes, int n_in,
                              void* d_out, int out_size, void* d_ws, size_t ws_size,
                              hipStream_t stream) {
  const float* x  = (const float*)d_in[0];
  const float* rw = (const float*)d_in[1];
  const float* rb = (const float*)d_in[2];
  const float* W1 = (const float*)d_in[3];
  const float* b1 = (const float*)d_in[4];
  const float* W2 = (const float*)d_in[5];
  const float* b2 = (const float*)d_in[6];
  float* out = (float*)d_out;

  char* ws = (char*)d_ws;
  int*    counts   = (int*)ws;
  int*    btok     = (int*)(ws + 256);
  float*  bw       = (float*)(ws + 256 + 262144);
  int*    tokrec   = (int*)(ws + 256 + 524288);
  int*    gcnt     = (int*)(ws + 655360);
  int2*   te_l     = (int2*)(ws + 720896);
  float2* tw       = (float2*)(ws + 786432);
  u16* xb  = (u16*)(ws + (1u << 20));
  u16* w1t = xb  + (size_t)NTOK * DIM_;
  u16* w2t = w1t + (size_t)E_ * H2_ * DIM_;
  u16* hb  = w2t + (size_t)E_ * DIM_ * HID_;
  u16* ybuf = w1t;  // 2 slabs x 32 MB aliasing w1t (dead after gemm1)

  prep<<<13312, 256, 0, stream>>>(W1, w1t, W2, w2t, x, rw, rb, xb, gcnt, te_l, tw);
  routerBC<<<32, 256, 0, stream>>>(gcnt, counts, te_l, tw, btok, bw, tokrec);

  gemm1<<<16384, 256, 0, stream>>>(xb, w1t, b1, counts, btok, hb);
  gemm2<<<8192, 256, 0, stream>>>(hb, w2t, b2, counts, bw, ybuf);
  combine<<<NTOK / 4, 256, 0, stream>>>(ybuf, tokrec, counts, out);
}

// Round 16
// 358.697 us; speedup vs baseline: 1.0961x; 1.0961x over previous
//
#include <hip/hip_runtime.h>
#include <stdint.h>

typedef unsigned short u16;

#define E_    8
#define DIM_  1024
#define HID_  2048
#define H2_   4096     // 2*HID
#define NTOK  8192     // B*T
#define SLAB  ((size_t)NTOK * 2 * DIM_)   // u16 elems per ybuf slab

typedef __attribute__((ext_vector_type(8))) short bf16x8;
typedef __attribute__((ext_vector_type(4))) float f32x4;

__device__ __forceinline__ u16 f2bf(float f) {
  uint32_t u = __builtin_bit_cast(uint32_t, f);
  uint32_t r = (u + 0x7FFFu + ((u >> 16) & 1u)) >> 16;
  return (u16)r;
}
__device__ __forceinline__ float bf2f(u16 u) {
  return __builtin_bit_cast(float, (uint32_t)u << 16);
}

__device__ __forceinline__ void gload16(const void* g, void* l) {
  __builtin_amdgcn_global_load_lds(
      (const __attribute__((address_space(1))) void*)g,
      (__attribute__((address_space(3))) void*)l, 16, 0, 0);
}

// ---------------- prep: fused weight transpose + router pass A ----------------

__global__ void prep(const float* __restrict__ W1, u16* __restrict__ w1t,
                     const float* __restrict__ W2, u16* __restrict__ w2t,
                     const float* __restrict__ x, const float* __restrict__ rw,
                     const float* __restrict__ rb, u16* __restrict__ xb,
                     int* __restrict__ gcnt, int2* __restrict__ te_l,
                     float2* __restrict__ tw) {
  __shared__ float smem[E_ * DIM_ + 16];
  int b = blockIdx.x;
  int tid = threadIdx.x;

  if (b < 12288) {
    float (*t)[65] = (float(*)[65])smem;
    const float* src; u16* dst; int R, C, e, bx, by;
    if (b < 8192) {
      e = b >> 10; int rem = b & 1023;
      bx = rem & 63; by = rem >> 6;
      src = W1; dst = w1t; R = DIM_; C = H2_;
    } else {
      int b2 = b - 8192;
      e = b2 >> 9; int rem = b2 & 511;
      bx = rem & 15; by = rem >> 4;
      src = W2; dst = w2t; R = HID_; C = DIM_;
    }
    int r0 = by * 64, c0 = bx * 64;
    const float* s = src + (size_t)e * R * C;
    u16* d = dst + (size_t)e * R * C;
    int rr = tid >> 4, cc = (tid & 15) * 4;
#pragma unroll
    for (int p = 0; p < 4; ++p) {
      float4 v = *(const float4*)(s + (size_t)(r0 + p * 16 + rr) * C + c0 + cc);
      t[p * 16 + rr][cc + 0] = v.x; t[p * 16 + rr][cc + 1] = v.y;
      t[p * 16 + rr][cc + 2] = v.z; t[p * 16 + rr][cc + 3] = v.w;
    }
    __syncthreads();
    int cr = tid >> 3, rc = (tid & 7) * 8;
#pragma unroll
    for (int p = 0; p < 2; ++p) {
      union { u16 u[8]; uint4 v; } w;
#pragma unroll
      for (int j = 0; j < 8; ++j) w.u[j] = f2bf(t[rc + j][p * 32 + cr]);
      *(uint4*)(d + (size_t)(c0 + p * 32 + cr) * R + r0 + rc) = w.v;
    }
  } else {
    int rblk = b - 12288;
    float* srw = smem;
    float* sb  = smem + E_ * DIM_;
    int*   hcnt = (int*)(smem + E_ * DIM_ + 8);

    for (int i = tid; i < E_ * DIM_ / 4; i += 256)
      ((float4*)srw)[i] = ((const float4*)rw)[i];
    if (tid < E_) { sb[tid] = rb[tid]; hcnt[tid] = 0; }
    __syncthreads();

    int wid = tid >> 6, lane = tid & 63;
#pragma unroll
    for (int s = 0; s < 2; ++s) {
      int t = rblk * 8 + wid * 2 + s;
      const float* xt = x + (size_t)t * DIM_;
      float acc[8] = {0.f, 0.f, 0.f, 0.f, 0.f, 0.f, 0.f, 0.f};
#pragma unroll
      for (int it = 0; it < 4; ++it) {
        int d = it * 256 + lane * 4;
        float4 xv = *(const float4*)(xt + d);
        ushort4 xo;
        xo.x = f2bf(xv.x); xo.y = f2bf(xv.y); xo.z = f2bf(xv.z); xo.w = f2bf(xv.w);
        *(ushort4*)(xb + (size_t)t * DIM_ + d) = xo;
#pragma unroll
        for (int e = 0; e < 8; ++e) {
          float4 rv = *(const float4*)(&srw[e * DIM_ + d]);
          acc[e] += xv.x * rv.x + xv.y * rv.y + xv.z * rv.z + xv.w * rv.w;
        }
      }
#pragma unroll
      for (int e = 0; e < 8; ++e)
#pragma unroll
        for (int off = 32; off; off >>= 1)
          acc[e] += __shfl_xor(acc[e], off, 64);
      if (lane == 0) {
        float v[8];
#pragma unroll
        for (int e = 0; e < 8; ++e) v[e] = acc[e] + sb[e];
        int i0 = 0;
#pragma unroll
        for (int e = 1; e < 8; ++e) if (v[e] > v[i0]) i0 = e;
        int i1 = (i0 == 0) ? 1 : 0;
#pragma unroll
        for (int e = 0; e < 8; ++e) if (e != i0 && v[e] > v[i1]) i1 = e;
        float w0 = 1.f / (1.f + expf(v[i1] - v[i0]));
        int l0 = atomicAdd(&hcnt[i0], 1);
        int l1 = atomicAdd(&hcnt[i1], 1);
        te_l[t] = make_int2((i0 << 8) | l0, (i1 << 8) | l1);
        tw[t] = make_float2(w0, 1.f - w0);
      }
    }
    __syncthreads();
    if (tid < E_) gcnt[tid * 1024 + rblk] = hcnt[tid];
  }
}

// ---------------- routerBC: redundant 8-expert batched scan + scatter ----------------

__global__ void routerBC(const int* __restrict__ gcnt, int* __restrict__ counts,
                         const int2* __restrict__ te_l, const float2* __restrict__ tw,
                         int* __restrict__ btok, float* __restrict__ bw,
                         int* __restrict__ tokrec) {
  __shared__ int part[8][256];
  __shared__ int sbb[8][32];
  int tid = threadIdx.x, b = blockIdx.x;

  int4 v[8]; int s[8];
#pragma unroll
  for (int e = 0; e < 8; ++e) {
    v[e] = *(const int4*)(gcnt + e * 1024 + tid * 4);
    s[e] = v[e].x + v[e].y + v[e].z + v[e].w;
    part[e][tid] = s[e];
  }
  __syncthreads();
  for (int off = 1; off < 256; off <<= 1) {
    int o[8];
#pragma unroll
    for (int e = 0; e < 8; ++e) o[e] = (tid >= off) ? part[e][tid - off] : 0;
    __syncthreads();
#pragma unroll
    for (int e = 0; e < 8; ++e) part[e][tid] += o[e];
    __syncthreads();
  }
  if ((tid >> 3) == b) {
    int lc = (tid & 7) * 4;
#pragma unroll
    for (int e = 0; e < 8; ++e) {
      int ex = part[e][tid] - s[e];
      sbb[e][lc + 0] = ex;
      sbb[e][lc + 1] = ex + v[e].x;
      sbb[e][lc + 2] = ex + v[e].x + v[e].y;
      sbb[e][lc + 3] = ex + v[e].x + v[e].y + v[e].z;
    }
  }
  if (b == 0 && tid < 8) counts[tid] = part[tid][255];
  __syncthreads();

  int t = b * 256 + tid;
  int2 r = te_l[t];
  float2 w = tw[t];
  int blk_l = tid >> 3;
  int e0 = r.x >> 8, l0 = r.x & 255;
  int e1 = r.y >> 8, l1 = r.y & 255;
  int p0 = sbb[e0][blk_l] + l0;
  int p1 = sbb[e1][blk_l] + l1;
  btok[e0 * NTOK + p0] = t; bw[e0 * NTOK + p0] = w.x; tokrec[t * 2 + 0] = (e0 << 13) | p0;
  btok[e1 * NTOK + p1] = t; bw[e1 * NTOK + p1] = w.y; tokrec[t * 2 + 1] = (e1 << 13) | p1;
}

// ---------------- GEMM1: gathered x @ W1 -> swiglu -> hb ----------------
// 1D grid 16384, XCD-chunked (one expert per XCD), nblk fastest within the
// chunk (R14 ordering — best measured): consecutive blocks share the SAME
// gathered A-tile back-to-back in L2; coalesced B streams.

__launch_bounds__(256, 4)
__global__ void gemm1(const u16* __restrict__ xb, const u16* __restrict__ w1t,
                      const float* __restrict__ b1, const int* __restrict__ counts,
                      const int* __restrict__ btok, u16* __restrict__ hb) {
  int bid = blockIdx.x;
  int swz = (bid & 7) * 2048 + (bid >> 3);
  int e = swz >> 11;
  int rem = swz & 2047;
  int mblk = rem >> 5, nblk = rem & 31;   // nblk fastest (R14)

  int cnt = counts[e];
  if (mblk * 128 >= cnt) return;
  int base = 0;
#pragma unroll
  for (int i = 0; i < 8; ++i) base += (i < e) ? counts[i] : 0;

  __shared__ u16 lA[128 * 64];
  __shared__ u16 lB[128 * 64];
  __shared__ int sTok[128];

  int tid = threadIdx.x, wid = tid >> 6, lane = tid & 63;
  if (tid < 128) {
    int gr = mblk * 128 + tid;
    sTok[tid] = (gr < cnt) ? btok[e * NTOK + gr] : btok[e * NTOK];
  }
  __syncthreads();

  f32x4 acc[4][4] = {};
  int wr = wid >> 1, wc = wid & 1;
  int l15 = lane & 15, lhi = lane >> 4;
  const size_t w1e = (size_t)e * H2_ * DIM_;

  int segsw = ((lane & 7) ^ ((lane >> 3) & 7)) * 8;
  const u16* gA[4];
  const u16* gB[4];
#pragma unroll
  for (int i = 0; i < 4; ++i) {
    int r = wid * 32 + i * 8 + (lane >> 3);
    gA[i] = xb + (size_t)sTok[r] * DIM_ + segsw;
    int gcol = nblk * 64 + (r >> 6) * 32 + (r & 31) + ((r >> 5) & 1) * 2048;
    gB[i] = w1t + w1e + (size_t)gcol * DIM_ + segsw;
  }
  int rxor = (l15 & 7) * 8;

  for (int kt = 0; kt < DIM_ / 64; ++kt) {
#pragma unroll
    for (int i = 0; i < 4; ++i)
      gload16(gA[i] + kt * 64, &lA[(wid * 32 + i * 8) * 64]);
#pragma unroll
    for (int i = 0; i < 4; ++i)
      gload16(gB[i] + kt * 64, &lB[(wid * 32 + i * 8) * 64]);
    __syncthreads();
#pragma unroll
    for (int ks = 0; ks < 2; ++ks) {
      int segrd = ((ks * 4 + lhi) * 8) ^ rxor;
      bf16x8 a[4], b[4];
#pragma unroll
      for (int m = 0; m < 4; ++m)
        a[m] = *(const bf16x8*)&lA[(wr * 64 + m * 16 + l15) * 64 + segrd];
#pragma unroll
      for (int n = 0; n < 4; ++n)
        b[n] = *(const bf16x8*)&lB[(wc * 64 + n * 16 + l15) * 64 + segrd];
#pragma unroll
      for (int m = 0; m < 4; ++m)
#pragma unroll
        for (int n = 0; n < 4; ++n)
          acc[m][n] = __builtin_amdgcn_mfma_f32_16x16x32_bf16(a[m], b[n], acc[m][n], 0, 0, 0);
    }
    __syncthreads();
  }

#pragma unroll
  for (int n = 0; n < 2; ++n) {
    int outcol = nblk * 64 + wc * 32 + n * 16 + l15;
    float bb1 = b1[e * H2_ + outcol];
    float bb2 = b1[e * H2_ + outcol + HID_];
#pragma unroll
    for (int m = 0; m < 4; ++m) {
#pragma unroll
      for (int j = 0; j < 4; ++j) {
        int rt = wr * 64 + m * 16 + lhi * 4 + j;
        int gr = mblk * 128 + rt;
        if (gr < cnt) {
          float h1 = acc[m][n][j] + bb1;
          float h2 = acc[m][n + 2][j] + bb2;
          float s = (h1 / (1.f + __expf(-h1))) * h2;
          hb[(size_t)(base + gr) * HID_ + outcol] = f2bf(s);
        }
      }
    }
  }
}

// ---------------- GEMM2 split-K=2, XCD-chunked 1D grid (R14 ordering) ----------------

__launch_bounds__(256, 4)
__global__ void gemm2(const u16* __restrict__ hb, const u16* __restrict__ w2t,
                      const float* __restrict__ b2, const int* __restrict__ counts,
                      const float* __restrict__ bw, u16* __restrict__ ybuf) {
  int bid = blockIdx.x;
  int swz = (bid & 7) * 1024 + (bid >> 3);
  int e = swz >> 10;
  int rem = swz & 1023;
  int mblk = rem >> 4;
  int nblk = rem & 7, khalf = (rem >> 3) & 1;   // R14 ordering

  int cnt = counts[e];
  if (mblk * 128 >= cnt) return;
  int base = 0;
#pragma unroll
  for (int i = 0; i < 8; ++i) base += (i < e) ? counts[i] : 0;

  __shared__ u16 lA[128 * 64];
  __shared__ u16 lB[128 * 64];
  __shared__ float sW[128];

  int tid = threadIdx.x, wid = tid >> 6, lane = tid & 63;
  if (tid < 128) {
    int gr = mblk * 128 + tid;
    sW[tid] = (gr < cnt) ? bw[e * NTOK + gr] : 0.f;
  }
  __syncthreads();

  f32x4 acc[4][4] = {};
  int wr = wid >> 1, wc = wid & 1;
  int l15 = lane & 15, lhi = lane >> 4;

  int segsw = ((lane & 7) ^ ((lane >> 3) & 7)) * 8;
  int koff = khalf * (HID_ / 2);
  const u16* gA[4];
  const u16* gB[4];
#pragma unroll
  for (int i = 0; i < 4; ++i) {
    int r = wid * 32 + i * 8 + (lane >> 3);
    gA[i] = hb + (size_t)(base + mblk * 128 + r) * HID_ + koff + segsw;
    gB[i] = w2t + (size_t)e * DIM_ * HID_ + (size_t)(nblk * 128 + r) * HID_ + koff + segsw;
  }
  int rxor = (l15 & 7) * 8;

  for (int kt = 0; kt < HID_ / 128; ++kt) {
#pragma unroll
    for (int i = 0; i < 4; ++i) {
      gload16(gA[i] + kt * 64, &lA[(wid * 32 + i * 8) * 64]);
      gload16(gB[i] + kt * 64, &lB[(wid * 32 + i * 8) * 64]);
    }
    __syncthreads();
#pragma unroll
    for (int ks = 0; ks < 2; ++ks) {
      int segrd = ((ks * 4 + lhi) * 8) ^ rxor;
      bf16x8 a[4], b[4];
#pragma unroll
      for (int m = 0; m < 4; ++m)
        a[m] = *(const bf16x8*)&lA[(wr * 64 + m * 16 + l15) * 64 + segrd];
#pragma unroll
      for (int n = 0; n < 4; ++n)
        b[n] = *(const bf16x8*)&lB[(wc * 64 + n * 16 + l15) * 64 + segrd];
#pragma unroll
      for (int m = 0; m < 4; ++m)
#pragma unroll
        for (int n = 0; n < 4; ++n)
          acc[m][n] = __builtin_amdgcn_mfma_f32_16x16x32_bf16(a[m], b[n], acc[m][n], 0, 0, 0);
    }
    __syncthreads();
  }

  u16* yb = ybuf + (size_t)khalf * SLAB;
#pragma unroll
  for (int n = 0; n < 4; ++n) {
    int col = nblk * 128 + wc * 64 + n * 16 + l15;
    float bb = (khalf == 0) ? b2[e * DIM_ + col] : 0.f;
#pragma unroll
    for (int m = 0; m < 4; ++m) {
#pragma unroll
      for (int j = 0; j < 4; ++j) {
        int rt = wr * 64 + m * 16 + lhi * 4 + j;
        int gr = mblk * 128 + rt;
        if (gr < cnt)
          yb[(size_t)(base + gr) * DIM_ + col] = f2bf(sW[rt] * (acc[m][n][j] + bb));
      }
    }
  }
}

// ---------------- combine: out[t] = sum of 4 slices ----------------

__global__ void combine(const u16* __restrict__ ybuf, const int* __restrict__ tokrec,
                        const int* __restrict__ counts, float* __restrict__ out) {
  __shared__ int sbase[8];
  int tid = threadIdx.x;
  if (tid < 8) {
    int b = 0;
#pragma unroll
    for (int e = 0; e < 8; ++e) { if (e == tid) sbase[e] = b; b += counts[e]; }
  }
  __syncthreads();
  int wid = tid >> 6, lane = tid & 63;
  int t = blockIdx.x * 4 + wid;
  int r0 = tokrec[t * 2 + 0], r1 = tokrec[t * 2 + 1];
  size_t s0 = (size_t)(sbase[r0 >> 13] + (r0 & 8191)) * DIM_;
  size_t s1 = (size_t)(sbase[r1 >> 13] + (r1 & 8191)) * DIM_;
#pragma unroll
  for (int p = 0; p < 4; ++p) {
    int c = (lane + p * 64) * 4;
    ushort4 a0 = *(const ushort4*)(ybuf + s0 + c);
    ushort4 a1 = *(const ushort4*)(ybuf + SLAB + s0 + c);
    ushort4 b0 = *(const ushort4*)(ybuf + s1 + c);
    ushort4 b1 = *(const ushort4*)(ybuf + SLAB + s1 + c);
    float4 o;
    o.x = bf2f(a0.x) + bf2f(a1.x) + bf2f(b0.x) + bf2f(b1.x);
    o.y = bf2f(a0.y) + bf2f(a1.y) + bf2f(b0.y) + bf2f(b1.y);
    o.z = bf2f(a0.z) + bf2f(a1.z) + bf2f(b0.z) + bf2f(b1.z);
    o.w = bf2f(a0.w) + bf2f(a1.w) + bf2f(b0.w) + bf2f(b1.w);
    *(float4*)(out + (size_t)t * DIM_ + c) = o;
  }
}

// ---------------- launch ----------------

extern "C" void kernel_launch(void* const* d_in, const int* in_sizes, int n_in,
                              void* d_out, int out_size, void* d_ws, size_t ws_size,
                              hipStream_t stream) {
  const float* x  = (const float*)d_in[0];
  const float* rw = (const float*)d_in[1];
  const float* rb = (const float*)d_in[2];
  const float* W1 = (const float*)d_in[3];
  const float* b1 = (const float*)d_in[4];
  const float* W2 = (const float*)d_in[5];
  const float* b2 = (const float*)d_in[6];
  float* out = (float*)d_out;

  char* ws = (char*)d_ws;
  int*    counts   = (int*)ws;
  int*    btok     = (int*)(ws + 256);
  float*  bw       = (float*)(ws + 256 + 262144);
  int*    tokrec   = (int*)(ws + 256 + 524288);
  int*    gcnt     = (int*)(ws + 655360);
  int2*   te_l     = (int2*)(ws + 720896);
  float2* tw       = (float2*)(ws + 786432);
  u16* xb  = (u16*)(ws + (1u << 20));
  u16* w1t = xb  + (size_t)NTOK * DIM_;
  u16* w2t = w1t + (size_t)E_ * H2_ * DIM_;
  u16* hb  = w2t + (size_t)E_ * DIM_ * HID_;
  u16* ybuf = w1t;  // 2 slabs x 32 MB aliasing w1t (dead after gemm1)

  prep<<<13312, 256, 0, stream>>>(W1, w1t, W2, w2t, x, rw, rb, xb, gcnt, te_l, tw);
  routerBC<<<32, 256, 0, stream>>>(gcnt, counts, te_l, tw, btok, bw, tokrec);

  gemm1<<<16384, 256, 0, stream>>>(xb, w1t, b1, counts, btok, hb);
  gemm2<<<8192, 256, 0, stream>>>(hb, w2t, b2, counts, bw, ybuf);
  combine<<<NTOK / 4, 256, 0, stream>>>(ybuf, tokrec, counts, out);
}